// Round 15
// baseline (74.605 us; speedup 1.0000x reference)
//
#include <hip/hip_runtime.h>
#include <hip/hip_bf16.h>
#include <stdint.h>

// Problem constants
#define KD 2304    // K = C*3*3
#define LD 3136    // L = 56*56
#define ND 256     // output channels
#define MD 25088   // B*L
#define CD 256     // input channels
#define PITCH 64   // padded row pitch (floats)
#define PROWS 58
#define PLANE (PROWS * PITCH)

typedef __bf16 bf16x8 __attribute__((ext_vector_type(8)));
typedef float f32x4 __attribute__((ext_vector_type(4)));
typedef float f32x4u __attribute__((ext_vector_type(4), aligned(4)));

__device__ __forceinline__ void gload_lds16(const void* g, void* l) {
  __builtin_amdgcn_global_load_lds(
      (const __attribute__((address_space(1))) unsigned int*)g,
      (__attribute__((address_space(3))) unsigned int*)l, 16, 0, 0);
}

// ---------- prep: pad x into [B*C][58][64] (bid<2048) + weight quant (else) ----------
__global__ __launch_bounds__(256) void prep_kernel(
    const float* __restrict__ x, float* __restrict__ xpad,
    const float* __restrict__ w, __hip_bfloat16* __restrict__ wqT) {
  if (blockIdx.x < 2048) {
    const int plane = blockIdx.x;
    const float* src = x + (size_t)plane * LD;
    float* dst = xpad + (size_t)plane * PLANE;
    const int cc4 = (threadIdx.x & 15) * 4;
    const int r0 = threadIdx.x >> 4;
#pragma unroll
    for (int p = 0; p < 4; ++p) {
      const int r = r0 + p * 16;
      if (r >= PROWS) continue;
      f32x4 o = {0.f, 0.f, 0.f, 0.f};
      if (r >= 1 && r <= 56) {
        const float* srow = src + (r - 1) * 56;
        if (cc4 == 0) {
          f32x4u v = *(const f32x4u*)(srow);
          o[1] = v[0]; o[2] = v[1]; o[3] = v[2];
        } else if (cc4 <= 52) {
          o = *(const f32x4u*)(srow + cc4 - 1);
        } else if (cc4 == 56) {
          f32x4u v = *(const f32x4u*)(srow + 52);
          o[0] = v[3];
        }
      }
      *(f32x4*)(dst + r * PITCH + cc4) = o;
    }
  } else {
    const int wb = blockIdx.x - 2048;            // 0..575
    const int gk = wb % 72;
    const int gn = wb / 72;
    const int n = gn * 32 + (threadIdx.x >> 3);
    const int k = gk * 32 + (threadIdx.x & 7) * 4;
    const float4 v = *(const float4*)(w + (size_t)n * KD + k);
    float a = fmaxf(fmaxf(fabsf(v.x), fabsf(v.y)), fmaxf(fabsf(v.z), fabsf(v.w)));
#pragma unroll
    for (int m = 1; m <= 32; m <<= 1) a = fmaxf(a, __shfl_xor(a, m, 64));
    __shared__ float red[4];
    if ((threadIdx.x & 63) == 0) red[threadIdx.x >> 6] = a;
    __syncthreads();
    const float mx = fmaxf(fmaxf(red[0], red[1]), fmaxf(red[2], red[3]));
    const float r63 = (mx == 0.f) ? 0.f : 63.f / mx;
    const float scale = mx * (1.f / 63.f);
    ushort4 o;
    o.x = __builtin_bit_cast(unsigned short, __float2bfloat16(rintf(v.x * r63) * scale));
    o.y = __builtin_bit_cast(unsigned short, __float2bfloat16(rintf(v.y * r63) * scale));
    o.z = __builtin_bit_cast(unsigned short, __float2bfloat16(rintf(v.z * r63) * scale));
    o.w = __builtin_bit_cast(unsigned short, __float2bfloat16(rintf(v.w * r63) * scale));
    *(ushort4*)((unsigned short*)wqT + (size_t)n * KD + k) = o;
  }
}

// ---- UNIFORM window prefetch: 5 channels x 3 rows = 15 loads (vmcnt-constant) ----
__device__ __forceinline__ void qload_u(const float* __restrict__ pb, int p0,
                                        int c0, f32x4u (&win)[5][3]) {
#pragma unroll
  for (int dc = 0; dc < 5; ++dc) {
    const int cdc = (c0 + dc > 255) ? 255 : c0 + dc;
    const float* cp = pb + p0 + cdc * PLANE;
#pragma unroll
    for (int di = 0; di < 3; ++di)
      win[dc][di] = *(const f32x4u*)(cp + di * PITCH);
  }
}

// ---- finish quant -> swizzled As write (256B rows, 16x16B units, u^(r&15)) ----
template <int KP0>
__device__ __forceinline__ void qfinishT(const f32x4u (&win)[5][3],
                                         char* __restrict__ as_row,
                                         unsigned swz, unsigned cbase) {
  float v[32];
#pragma unroll
  for (int t = 0; t < 32; ++t) {
    const int idx = KP0 + t;
    v[t] = win[idx / 9][(idx % 9) / 3][(idx % 9) % 3];
  }
  float m16[16];
#pragma unroll
  for (int t = 0; t < 16; ++t)
    m16[t] = fmaxf(__builtin_fabsf(v[2 * t]), __builtin_fabsf(v[2 * t + 1]));
#pragma unroll
  for (int t = 0; t < 8; ++t) m16[t] = fmaxf(m16[t], m16[t + 8]);
#pragma unroll
  for (int t = 0; t < 4; ++t) m16[t] = fmaxf(m16[t], m16[t + 4]);
  const float mx = fmaxf(fmaxf(m16[0], m16[1]), fmaxf(m16[2], m16[3]));
  float r63 = 63.f * __builtin_amdgcn_rcpf(mx);
  r63 = (mx == 0.f) ? 0.f : r63;
  const float scale = mx * (1.f / 63.f);
  unsigned pk[16];
#pragma unroll
  for (int t = 0; t < 16; ++t) {
    const float a = rintf(v[2 * t] * r63) * scale;
    const float b = rintf(v[2 * t + 1] * r63) * scale;
    unsigned d;
    asm("v_cvt_pk_bf16_f32 %0, %1, %2" : "=v"(d) : "v"(a), "v"(b));
    pk[t] = d;
  }
#pragma unroll
  for (int s = 0; s < 4; ++s) {
    uint4 o = {pk[4 * s], pk[4 * s + 1], pk[4 * s + 2], pk[4 * s + 3]};
    *(uint4*)(as_row + ((cbase + (unsigned)(s * 16)) ^ swz)) = o;
  }
}

#define SW_FIN(PH, ROW, SWZ, CB)                                              \
  switch (PH) {                                                               \
    case 0: qfinishT<0>(win, ROW, SWZ, CB); break;                            \
    case 1: qfinishT<1>(win, ROW, SWZ, CB); break;                            \
    case 2: qfinishT<2>(win, ROW, SWZ, CB); break;                            \
    case 3: qfinishT<3>(win, ROW, SWZ, CB); break;                            \
    case 4: qfinishT<4>(win, ROW, SWZ, CB); break;                            \
    case 5: qfinishT<5>(win, ROW, SWZ, CB); break;                            \
    case 6: qfinishT<6>(win, ROW, SWZ, CB); break;                            \
    case 7: qfinishT<7>(win, ROW, SWZ, CB); break;                            \
    default: qfinishT<8>(win, ROW, SWZ, CB); break;                           \
  }

// ---- stage 256n x 128k wqT tile (64KB, 256B rows, u^(r&15) via source) ----
// 64 chunks of 1KB (4 rows x 256B); 8 per wave -> vmcnt contribution = 8/wave.
__device__ __forceinline__ void stage_ns(const unsigned short* __restrict__ wsrc,
                                         int k0, int lane, int w,
                                         char* __restrict__ Ns) {
#pragma unroll
  for (int sg = 0; sg < 8; ++sg) {
    const int c = w * 8 + sg;              // 0..63
    const int row = c * 4 + (lane >> 4);   // 0..255
    const int u = (lane & 15) ^ (row & 15);
    gload_lds16(wsrc + (size_t)row * KD + k0 + u * 8, Ns + c * 1024 + lane * 16);
  }
}

// ---- MFMA: 8 waves (wn = w&3, wm = w>>2), wave tile 64n x 64m, BK=128 ----
__device__ __forceinline__ void mfma_phase(const char* __restrict__ As,
                                           const char* __restrict__ Ns,
                                           f32x4 (&acc)[4][4], int wn, int wm,
                                           int lq, int hv) {
#pragma unroll
  for (int kk = 0; kk < 4; ++kk) {
    bf16x8 af[4], bf[4];
#pragma unroll
    for (int i = 0; i < 4; ++i) {
      const unsigned rn = (unsigned)(wn * 64 + i * 16 + lq);
      const unsigned u = (unsigned)((kk * 4 + hv) ^ (rn & 15));
      af[i] = *(const bf16x8*)(Ns + rn * 256u + u * 16u);
    }
#pragma unroll
    for (int j = 0; j < 4; ++j) {
      const unsigned rm = (unsigned)(wm * 64 + j * 16 + lq);
      const unsigned u = (unsigned)((kk * 4 + hv) ^ (rm & 15));
      bf[j] = *(const bf16x8*)(As + rm * 256u + u * 16u);
    }
#pragma unroll
    for (int i = 0; i < 4; ++i)
#pragma unroll
      for (int j = 0; j < 4; ++j)
        acc[i][j] = __builtin_amdgcn_mfma_f32_16x16x32_bf16(
            af[i], bf[j], acc[i][j], 0, 0, 0);
  }
}

// ---------------- Fused: BM=128, BN=256, BK=128, 8 waves, 196 blocks ----------------
// 1 block/CU (no 2-block LDS contention, no imbalance). LDS 96KB single-buffered.
// Quant-once: 512 granules/step = 1/thread; wave (wm=w>>2, ks=w&3) quantizes rows
// wm*64+lane, k-slot ks. Step: stage Ns(R) -> qfinish(R)->As -> qload win(R+1)
// (15 loads cross bar) -> bar1{vmcnt(15),lgkm0} -> MFMA (setprio) -> bar2{lgkm0}.
__global__ __launch_bounds__(512, 2) void fused_gemm_kernel(
    const float* __restrict__ xpad, const __hip_bfloat16* __restrict__ wqT,
    const float* __restrict__ bias, float* __restrict__ out) {
  extern __shared__ char smem[];
  char* As = smem;            // 128 rows x 256B = 32KB
  char* Ns = smem + 32768;    // 256 rows x 256B = 64KB
  const int tid = threadIdx.x;
  const int lane = tid & 63;
  const int w = __builtin_amdgcn_readfirstlane(tid >> 6);   // 0..7
  const int wm = w >> 2, ks = w & 3, wn = w & 3;

  // block -> m-tile, XCD-grouped bijective (196 = 4*25 + 4*24)
  const int bid = blockIdx.x;
  const int xcd = bid & 7;
  const int idx = bid >> 3;
  const int mt = (xcd < 4) ? (xcd * 25 + idx) : (100 + (xcd - 4) * 24 + idx);
  const int m0 = mt * 128;

  // quant geometry: wave rows = m0 + wm*64 + lane (64-aligned -> b uniform/wave)
  const int gb = m0 + wm * 64;
  const int b = gb / LD;
  const int l = gb - b * LD + lane;
  const int i = l / 56;
  const int j = l - i * 56;
  const float* pb = xpad + (size_t)b * CD * PLANE;
  const int p0 = i * PITCH + j;
  char* as_row = As + (wm * 64 + lane) * 256;
  const unsigned swz = (unsigned)((lane & 15) << 4);
  const unsigned cb = (unsigned)(ks * 64);
  const unsigned short* wsrc = (const unsigned short*)wqT;

  const int lq = lane & 15, hv = lane >> 4;

  f32x4 acc[4][4] = {};
  f32x4u win[5][3];

  // prologue: win for step-0 granule (k = 32*ks); ph init {0,5,1,6}
  int kq = 32 * ks;
  int ph = kq % 9;
  qload_u(pb, p0, kq / 9, win);

  for (int R = 0; R < 18; ++R) {
    stage_ns(wsrc, R * 128, lane, w, Ns);        // 8 async gload_lds -> Ns
    __builtin_amdgcn_sched_barrier(0);           // pin: stage before quant

    SW_FIN(ph, as_row, swz, cb);                 // consume win -> As

    kq += 128;
    ph += 2; if (ph >= 9) ph -= 9;
    qload_u(pb, p0, kq / 9, win);                // 15 loads cross bar1 (tail clamped)

    // drain the 8 stage loads (older), keep the 15 win loads in flight
    asm volatile("s_waitcnt vmcnt(15) lgkmcnt(0)\n\ts_barrier" ::: "memory");
    __builtin_amdgcn_sched_barrier(0);

    __builtin_amdgcn_s_setprio(1);
    mfma_phase(As, Ns, acc, wn, wm, lq, hv);
    __builtin_amdgcn_s_setprio(0);

    asm volatile("s_waitcnt lgkmcnt(0)\n\ts_barrier" ::: "memory");
    __builtin_amdgcn_sched_barrier(0);
  }

  // ---- Epilogue: D row = n = wn*64 + i4*16 + hv*4 + comp, col = m (coalesced) ----
#pragma unroll
  for (int i4 = 0; i4 < 4; ++i4) {
    const int nb = wn * 64 + i4 * 16 + hv * 4;
    const float4 b4 = *(const float4*)&bias[nb];
#pragma unroll
    for (int j4 = 0; j4 < 4; ++j4) {
      const int m = m0 + wm * 64 + j4 * 16 + lq;
      const int ll = m - b * LD;                 // same b as quant wave group
      float* op = out + ((size_t)b * ND + nb) * LD + ll;
      op[0]      = acc[i4][j4].x + b4.x;
      op[LD]     = acc[i4][j4].y + b4.y;
      op[2 * LD] = acc[i4][j4].z + b4.z;
      op[3 * LD] = acc[i4][j4].w + b4.w;
    }
  }
}

extern "C" void kernel_launch(void* const* d_in, const int* in_sizes, int n_in,
                              void* d_out, int out_size, void* d_ws, size_t ws_size,
                              hipStream_t stream) {
  const float* x = (const float*)d_in[0];
  const float* wgt = (const float*)d_in[1];
  const float* bias = (const float*)d_in[2];
  float* out = (float*)d_out;

  float* xpad = (float*)d_ws;                         // 30,408,704 B
  __hip_bfloat16* wqT = (__hip_bfloat16*)((char*)d_ws + 30408704);  // 1,179,648 B

  prep_kernel<<<2048 + 576, 256, 0, stream>>>(x, xpad, wgt, wqT);
  fused_gemm_kernel<<<196, 512, 96 * 1024, stream>>>(xpad, wqT, bias, out);
}